// Round 1
// baseline (189.330 us; speedup 1.0000x reference)
//
#include <hip/hip_runtime.h>
#include <math.h>

#define BB 1024
#define NN 256
#define VV 200

// Static device scratch (sidesteps ws_size uncertainty; fully rewritten every call)
__device__ float g_M[256];          // M_up[98] | M_dn[98] @98 | M_pv[49] @196
__device__ float g_x[3 * BB * VV];  // u, d, p  (pre-BN attention outputs)
__device__ float g_mean[3 * VV];
__device__ float g_rstd[3 * VV];

// ---------------- K0: M = Wq @ Wk^T (tiny) ----------------
__global__ __launch_bounds__(256) void k_prep(const float* __restrict__ upWq, const float* __restrict__ upWk,
                                              const float* __restrict__ dnWq, const float* __restrict__ dnWk,
                                              const float* __restrict__ pvWq, const float* __restrict__ pvWk) {
    int t = threadIdx.x;
    if (t < 98) {
        int i = t / 14, f = t % 14;
        float s = 0.f;
        for (int v = 0; v < VV; v++) s += upWq[i * VV + v] * upWk[f * VV + v];
        g_M[t] = s;
    } else if (t < 196) {
        int j = t - 98;
        int i = j / 14, f = j % 14;
        float s = 0.f;
        for (int v = 0; v < VV; v++) s += dnWq[i * VV + v] * dnWk[f * VV + v];
        g_M[t] = s;
    } else if (t < 245) {
        int j = t - 196;
        int i = j / 7, f = j % 7;
        float s = 0.f;
        for (int v = 0; v < VV; v++) s += pvWq[i * VV + v] * pvWk[f * VV + v];
        g_M[t] = s;
    }
}

// ---------------- K1: attention, one block per batch row ----------------
__global__ __launch_bounds__(256) void k_attn(const float* __restrict__ merged, const float* __restrict__ a,
                                              const float* __restrict__ upWv, const float* __restrict__ dnWv,
                                              const float* __restrict__ pvWv) {
    int b = blockIdx.x;
    int tid = threadIdx.x;
    int lane = tid & 63, wave = tid >> 6;

    __shared__ float sm[NN * 15];
    __shared__ float eM[14];
    __shared__ float red[4 * 14];
    __shared__ float csh[14];
    __shared__ float s4[4];

    const float* mb = merged + (size_t)b * NN * 15;
    for (int i = tid; i < NN * 15; i += 256) sm[i] = mb[i];
    __syncthreads();

    float subj_id = sm[0];
    float subj_loc = sm[2];
    float ab = a[b];
    float ego[7];
    ego[0] = 0.f;  // sm[0] - subj_id
    ego[1] = sm[1]; ego[2] = sm[2]; ego[3] = sm[3];
    ego[4] = sm[4]; ego[5] = sm[5]; ego[6] = ab;

    float feat[14];
    for (int f = 0; f < 14; f++) feat[f] = sm[tid * 15 + f];
    float flag = sm[tid * 15 + 14];
    feat[0] -= subj_id;
    feat[7] -= subj_id;
    if (tid == 0) feat[6] = ab;   // merged[:,0,6] = a
    float loc = feat[2];          // feature 2 untouched by shifts

    bool msk[3];
    msk[0] = (loc < subj_loc) && (flag == 1.f);
    msk[1] = (loc > subj_loc) && (flag == 1.f);
    msk[2] = (flag == 0.f);

    const float scale = 7.0710678118654752e-2f;  // 1/sqrt(200)

    const float* Wvs[3] = {upWv, dnWv, pvWv};
    const int Fs[3] = {14, 14, 7};
    const int Moff[3] = {0, 98, 196};

    for (int k = 0; k < 3; k++) {
        const int F = Fs[k];
        __syncthreads();  // protect eM / csh / s4 reuse
        if (tid < F) {
            float s = 0.f;
            const float* M = g_M + Moff[k];
            for (int i = 0; i < 7; i++) s += ego[i] * M[i * F + tid];
            eM[tid] = s;
        }
        __syncthreads();

        float s = 0.f;
        for (int f = 0; f < F; f++) s += eM[f] * feat[f];
        s *= scale;
        if (!msk[k]) s = -1e9f;

        // block max
        float m = s;
        for (int off = 32; off; off >>= 1) m = fmaxf(m, __shfl_down(m, off));
        if (lane == 0) s4[wave] = m;
        __syncthreads();
        m = fmaxf(fmaxf(s4[0], s4[1]), fmaxf(s4[2], s4[3]));

        float e = expf(s - m);
        float Z = e;
        for (int off = 32; off; off >>= 1) Z += __shfl_down(Z, off);
        __syncthreads();
        if (lane == 0) s4[wave] = Z;
        __syncthreads();
        Z = s4[0] + s4[1] + s4[2] + s4[3];
        float p = e / Z;

        // c[f] = sum_n p[n]*feat[n][f]
        float pf[14];
        for (int f = 0; f < F; f++) pf[f] = p * feat[f];
        for (int off = 32; off; off >>= 1)
            for (int f = 0; f < F; f++) pf[f] += __shfl_down(pf[f], off);
        if (lane == 0)
            for (int f = 0; f < F; f++) red[wave * 14 + f] = pf[f];
        __syncthreads();
        if (tid < F) csh[tid] = red[tid] + red[14 + tid] + red[28 + tid] + red[42 + tid];
        __syncthreads();

        if (tid < VV) {
            float val = 0.f;
            const float* Wv = Wvs[k];
            for (int f = 0; f < F; f++) val += csh[f] * Wv[f * VV + tid];
            if (m == -1e9f) val = 0.f;  // mask.any() == False
            g_x[((size_t)k * BB + b) * VV + tid] = val;
        }
    }
}

// ---------------- K2: BN stats over batch ----------------
__global__ __launch_bounds__(256) void k_stats() {
    int col = blockIdx.x;  // 0..599 : k*200+v
    int tid = threadIdx.x;
    int lane = tid & 63, wave = tid >> 6;
    const float* x = g_x + (size_t)(col / VV) * (BB * VV) + (col % VV);
    float s = 0.f, s2 = 0.f;
    for (int b = tid; b < BB; b += 256) {
        float v = x[(size_t)b * VV];
        s += v;
        s2 += v * v;
    }
    __shared__ float sh[8];
    for (int off = 32; off; off >>= 1) {
        s += __shfl_down(s, off);
        s2 += __shfl_down(s2, off);
    }
    if (lane == 0) { sh[wave] = s; sh[4 + wave] = s2; }
    __syncthreads();
    if (tid == 0) {
        s = sh[0] + sh[1] + sh[2] + sh[3];
        s2 = sh[4] + sh[5] + sh[6] + sh[7];
        float m = s * (1.f / BB);
        float var = s2 * (1.f / BB) - m * m;
        g_mean[col] = m;
        g_rstd[col] = rsqrtf(var + 1e-5f);
    }
}

// ---------------- K3: BN apply + trunk GEMMs + e-MLP + final sum ----------------
__global__ __launch_bounds__(256) void k_final(const float* __restrict__ merged, const float* __restrict__ a,
                                               const float* __restrict__ tW1, const float* __restrict__ tb1,
                                               const float* __restrict__ tW2, const float* __restrict__ tb2,
                                               const float* __restrict__ eW1, const float* __restrict__ eb1,
                                               const float* __restrict__ eW2, const float* __restrict__ eb2,
                                               const float* __restrict__ eW3, const float* __restrict__ eb3,
                                               const float* __restrict__ gamma, const float* __restrict__ beta,
                                               float* __restrict__ out) {
    int b0 = blockIdx.x * 4;
    int tid = threadIdx.x;
    int lane = tid & 63, wave = tid >> 6;

    __shared__ float tsh[4 * 3 * VV];  // [bb][k][v]
    __shared__ float q1sh[4 * VV];
    __shared__ float redsh[4 * 4];

    for (int idx = tid; idx < 4 * 3 * VV; idx += 256) {
        int bb = idx / (3 * VV);
        int rem = idx % (3 * VV);
        int k = rem / VV, v = rem % VV;
        float val = g_x[((size_t)k * BB + b0 + bb) * VV + v];
        tsh[idx] = gamma[v] * (val - g_mean[k * VV + v]) * g_rstd[k * VV + v] + beta[v];
    }
    __syncthreads();

    float fin[4] = {0.f, 0.f, 0.f, 0.f};
    int w = tid;
    if (w < VV) {
        for (int k = 0; k < 3; k++) {
            float bias = tb1[k * VV + w];
            float a0 = bias, a1 = bias, a2 = bias, a3 = bias;
            const float* W1 = tW1 + (size_t)k * VV * VV + w;
            const float* t0 = tsh + (0 * 3 + k) * VV;
            const float* t1 = tsh + (1 * 3 + k) * VV;
            const float* t2 = tsh + (2 * 3 + k) * VV;
            const float* t3 = tsh + (3 * 3 + k) * VV;
            for (int v = 0; v < VV; v++) {
                float w1 = W1[(size_t)v * VV];
                a0 += t0[v] * w1; a1 += t1[v] * w1; a2 += t2[v] * w1; a3 += t3[v] * w1;
            }
            float w2 = tW2[k * VV + w];
            a0 = a0 > 0.f ? a0 : expf(a0) - 1.f;
            a1 = a1 > 0.f ? a1 : expf(a1) - 1.f;
            a2 = a2 > 0.f ? a2 : expf(a2) - 1.f;
            a3 = a3 > 0.f ? a3 : expf(a3) - 1.f;
            fin[0] += a0 * w2; fin[1] += a1 * w2; fin[2] += a2 * w2; fin[3] += a3 * w2;
        }
        // e-MLP layer 1 : ego_t = merged[b,0,{3,4,5}] and a[b] (feature 6 := a)
        for (int bb = 0; bb < 4; bb++) {
            const float* mrow = merged + (size_t)(b0 + bb) * NN * 15;
            float q = eb1[w] + mrow[3] * eW1[w] + mrow[4] * eW1[VV + w] + mrow[5] * eW1[2 * VV + w] +
                      a[b0 + bb] * eW1[3 * VV + w];
            q1sh[bb * VV + w] = fmaxf(q, 0.f);
        }
    }
    __syncthreads();
    if (w < VV) {
        float bias = eb2[w];
        float a0 = bias, a1 = bias, a2 = bias, a3 = bias;
        const float* W2p = eW2 + w;
        for (int v = 0; v < VV; v++) {
            float w2v = W2p[(size_t)v * VV];
            a0 += q1sh[0 * VV + v] * w2v; a1 += q1sh[1 * VV + v] * w2v;
            a2 += q1sh[2 * VV + v] * w2v; a3 += q1sh[3 * VV + v] * w2v;
        }
        float w3 = eW3[w];
        fin[0] += fmaxf(a0, 0.f) * w3;
        fin[1] += fmaxf(a1, 0.f) * w3;
        fin[2] += fmaxf(a2, 0.f) * w3;
        fin[3] += fmaxf(a3, 0.f) * w3;
    }
    // block reduce the 4 scalars
    for (int off = 32; off; off >>= 1)
        for (int bb = 0; bb < 4; bb++) fin[bb] += __shfl_down(fin[bb], off);
    if (lane == 0)
        for (int bb = 0; bb < 4; bb++) redsh[wave * 4 + bb] = fin[bb];
    __syncthreads();
    if (tid < 4) {
        float tot = redsh[tid] + redsh[4 + tid] + redsh[8 + tid] + redsh[12 + tid];
        tot += eb3[0] + tb2[0] + tb2[1] + tb2[2];
        out[b0 + tid] = tot;
    }
}

extern "C" void kernel_launch(void* const* d_in, const int* in_sizes, int n_in,
                              void* d_out, int out_size, void* d_ws, size_t ws_size,
                              hipStream_t stream) {
    const float* merged = (const float*)d_in[0];
    const float* a      = (const float*)d_in[1];
    const float* upWq   = (const float*)d_in[2];
    const float* upWk   = (const float*)d_in[3];
    const float* upWv   = (const float*)d_in[4];
    const float* dnWq   = (const float*)d_in[5];
    const float* dnWk   = (const float*)d_in[6];
    const float* dnWv   = (const float*)d_in[7];
    const float* pvWq   = (const float*)d_in[8];
    const float* pvWk   = (const float*)d_in[9];
    const float* pvWv   = (const float*)d_in[10];
    const float* tW1    = (const float*)d_in[11];
    const float* tb1    = (const float*)d_in[12];
    const float* tW2    = (const float*)d_in[13];
    const float* tb2    = (const float*)d_in[14];
    const float* eW1    = (const float*)d_in[15];
    const float* eb1    = (const float*)d_in[16];
    const float* eW2    = (const float*)d_in[17];
    const float* eb2    = (const float*)d_in[18];
    const float* eW3    = (const float*)d_in[19];
    const float* eb3    = (const float*)d_in[20];
    const float* gamma  = (const float*)d_in[21];
    const float* beta   = (const float*)d_in[22];
    float* out = (float*)d_out;

    hipLaunchKernelGGL(k_prep, dim3(1), dim3(256), 0, stream, upWq, upWk, dnWq, dnWk, pvWq, pvWk);
    hipLaunchKernelGGL(k_attn, dim3(BB), dim3(256), 0, stream, merged, a, upWv, dnWv, pvWv);
    hipLaunchKernelGGL(k_stats, dim3(600), dim3(256), 0, stream);
    hipLaunchKernelGGL(k_final, dim3(BB / 4), dim3(256), 0, stream, merged, a,
                       tW1, tb1, tW2, tb2, eW1, eb1, eW2, eb2, eW3, eb3, gamma, beta, out);
}

// Round 2
// 176.730 us; speedup vs baseline: 1.0713x; 1.0713x over previous
//
#include <hip/hip_runtime.h>
#include <math.h>

#define BB 1024
#define NN 256
#define VV 200
#define BT 16   // batch rows per k_final block

// Static device scratch (fully rewritten every call)
__device__ float g_M[256];          // M_up[98] | M_dn[98] @98 | M_pv[49] @196
__device__ float g_x[3 * BB * VV];  // u, d, p  (pre-BN attention outputs)
__device__ float g_mean[3 * VV];
__device__ float g_rstd[3 * VV];

// ---------------- K0: M = Wq @ Wk^T, one block per head ----------------
__global__ __launch_bounds__(256) void k_prep(const float* __restrict__ upWq, const float* __restrict__ upWk,
                                              const float* __restrict__ dnWq, const float* __restrict__ dnWk,
                                              const float* __restrict__ pvWq, const float* __restrict__ pvWk) {
    __shared__ float wq[7 * VV];
    __shared__ float wk[14 * VV];
    int blk = blockIdx.x, tid = threadIdx.x;
    const float* Wq = blk == 0 ? upWq : (blk == 1 ? dnWq : pvWq);
    const float* Wk = blk == 0 ? upWk : (blk == 1 ? dnWk : pvWk);
    int F = (blk == 2) ? 7 : 14;
    int off = blk == 0 ? 0 : (blk == 1 ? 98 : 196);
    for (int i = tid; i < 7 * VV; i += 256) wq[i] = Wq[i];
    for (int i = tid; i < F * VV; i += 256) wk[i] = Wk[i];
    __syncthreads();
    if (tid < 7 * F) {
        int i = tid / F, f = tid % F;
        float s = 0.f;
        for (int v = 0; v < VV; v++) s += wq[i * VV + v] * wk[f * VV + v];
        g_M[off + tid] = s;  // layout: i*F + f  (matches k_attn's M[i*F + tid])
    }
}

// ---------------- K1: attention, one block per batch row ----------------
__global__ __launch_bounds__(256) void k_attn(const float* __restrict__ merged, const float* __restrict__ a,
                                              const float* __restrict__ upWv, const float* __restrict__ dnWv,
                                              const float* __restrict__ pvWv) {
    int b = blockIdx.x;
    int tid = threadIdx.x;
    int lane = tid & 63, wave = tid >> 6;

    __shared__ float sm[NN * 15];
    __shared__ float eM[14];
    __shared__ float red[4 * 14];
    __shared__ float csh[14];
    __shared__ float s4[4];

    const float* mb = merged + (size_t)b * NN * 15;
    // 256*15 floats = 960 float4; rows are 60B but whole-block buffer is 16B-divisible
    const float4* mb4 = (const float4*)mb;
    float4* sm4 = (float4*)sm;
    for (int i = tid; i < NN * 15 / 4; i += 256) sm4[i] = mb4[i];
    __syncthreads();

    float subj_id = sm[0];
    float subj_loc = sm[2];
    float ab = a[b];
    float ego[7];
    ego[0] = 0.f;  // sm[0] - subj_id
    ego[1] = sm[1]; ego[2] = sm[2]; ego[3] = sm[3];
    ego[4] = sm[4]; ego[5] = sm[5]; ego[6] = ab;

    float feat[14];
    for (int f = 0; f < 14; f++) feat[f] = sm[tid * 15 + f];
    float flag = sm[tid * 15 + 14];
    feat[0] -= subj_id;
    feat[7] -= subj_id;
    if (tid == 0) feat[6] = ab;   // merged[:,0,6] = a
    float loc = feat[2];          // feature 2 untouched by shifts

    bool msk[3];
    msk[0] = (loc < subj_loc) && (flag == 1.f);
    msk[1] = (loc > subj_loc) && (flag == 1.f);
    msk[2] = (flag == 0.f);

    const float scale = 7.0710678118654752e-2f;  // 1/sqrt(200)

    const float* Wvs[3] = {upWv, dnWv, pvWv};
    const int Fs[3] = {14, 14, 7};
    const int Moff[3] = {0, 98, 196};

    for (int k = 0; k < 3; k++) {
        const int F = Fs[k];
        __syncthreads();  // protect eM / csh / s4 reuse
        if (tid < F) {
            float s = 0.f;
            const float* M = g_M + Moff[k];
            for (int i = 0; i < 7; i++) s += ego[i] * M[i * F + tid];
            eM[tid] = s;
        }
        __syncthreads();

        float s = 0.f;
        for (int f = 0; f < F; f++) s += eM[f] * feat[f];
        s *= scale;
        if (!msk[k]) s = -1e9f;

        // block max
        float m = s;
        for (int off = 32; off; off >>= 1) m = fmaxf(m, __shfl_down(m, off));
        if (lane == 0) s4[wave] = m;
        __syncthreads();
        m = fmaxf(fmaxf(s4[0], s4[1]), fmaxf(s4[2], s4[3]));

        float e = expf(s - m);
        float Z = e;
        for (int off = 32; off; off >>= 1) Z += __shfl_down(Z, off);
        __syncthreads();
        if (lane == 0) s4[wave] = Z;
        __syncthreads();
        Z = s4[0] + s4[1] + s4[2] + s4[3];
        float p = e / Z;

        // c[f] = sum_n p[n]*feat[n][f]
        float pf[14];
        for (int f = 0; f < F; f++) pf[f] = p * feat[f];
        for (int off = 32; off; off >>= 1)
            for (int f = 0; f < F; f++) pf[f] += __shfl_down(pf[f], off);
        if (lane == 0)
            for (int f = 0; f < F; f++) red[wave * 14 + f] = pf[f];
        __syncthreads();
        if (tid < F) csh[tid] = red[tid] + red[14 + tid] + red[28 + tid] + red[42 + tid];
        __syncthreads();

        if (tid < VV) {
            float val = 0.f;
            const float* Wv = Wvs[k];
            for (int f = 0; f < F; f++) val += csh[f] * Wv[f * VV + tid];
            if (m == -1e9f) val = 0.f;  // mask.any() == False
            g_x[((size_t)k * BB + b) * VV + tid] = val;
        }
    }
}

// ---------------- K2: BN stats over batch (8 cols/block, 32B-coalesced) ----------------
__global__ __launch_bounds__(256) void k_stats() {
    int col0 = blockIdx.x * 8;            // 75 blocks; 200 = 25*8 so no k straddle
    int tv = threadIdx.x & 7, tb = threadIdx.x >> 3;   // tb in 0..31
    int k = col0 / VV, v = col0 % VV + tv;
    const float* x = g_x + (size_t)k * BB * VV + v;
    float s = 0.f, s2 = 0.f;
    for (int b = tb; b < BB; b += 32) {
        float val = x[(size_t)b * VV];
        s += val; s2 += val * val;
    }
    __shared__ float shs[256], shs2[256];
    shs[threadIdx.x] = s; shs2[threadIdx.x] = s2;
    __syncthreads();
    if (threadIdx.x < 8) {
        float S = 0.f, S2 = 0.f;
        for (int j = threadIdx.x; j < 256; j += 8) { S += shs[j]; S2 += shs2[j]; }
        float m = S * (1.f / BB);
        float var = S2 * (1.f / BB) - m * m;
        g_mean[col0 + threadIdx.x] = m;
        g_rstd[col0 + threadIdx.x] = rsqrtf(var + 1e-5f);
    }
}

// ---------------- K3: BN apply + trunk GEMM / e-MLP, 16 rows x 4 col-groups ----------------
// grid = 64 tiles * 4 groups. q<3: trunk head k=q. q==3: e-MLP. Partials atomicAdd'ed.
__global__ __launch_bounds__(256) void k_final(const float* __restrict__ merged, const float* __restrict__ a,
                                               const float* __restrict__ tW1, const float* __restrict__ tb1,
                                               const float* __restrict__ tW2, const float* __restrict__ tb2,
                                               const float* __restrict__ eW1, const float* __restrict__ eb1,
                                               const float* __restrict__ eW2, const float* __restrict__ eb2,
                                               const float* __restrict__ eW3, const float* __restrict__ eb3,
                                               const float* __restrict__ gamma, const float* __restrict__ beta,
                                               float* __restrict__ out) {
    int tile = blockIdx.x >> 2;
    int q = blockIdx.x & 3;
    int b0 = tile * BT;
    int tid = threadIdx.x;
    int lane = tid & 63, wave = tid >> 6;
    int w = tid;

    __shared__ float tT[VV * BT];      // transposed operand tile: [v][bb]
    __shared__ float redsh[4 * BT];
    __shared__ float esh[BT][4];

    float fin[BT];
#pragma unroll
    for (int bb = 0; bb < BT; bb++) fin[bb] = 0.f;

    if (q < 3) {
        // stage BN(t) transposed: tT[v*BT+bb]
        for (int idx = tid; idx < BT * VV; idx += 256) {
            int v = idx % VV, bb = idx / VV;
            float val = g_x[((size_t)q * BB + b0 + bb) * VV + v];
            tT[v * BT + bb] = gamma[v] * (val - g_mean[q * VV + v]) * g_rstd[q * VV + v] + beta[v];
        }
        __syncthreads();

        if (w < VV) {
            float acc[BT];
            float bias = tb1[q * VV + w];
#pragma unroll
            for (int bb = 0; bb < BT; bb++) acc[bb] = bias;
            const float* W1 = tW1 + (size_t)q * VV * VV + w;
            const float4* tT4 = (const float4*)tT;
#pragma unroll 4
            for (int v = 0; v < VV; v++) {
                float w1 = W1[(size_t)v * VV];
                float4 t0 = tT4[v * 4 + 0];
                float4 t1 = tT4[v * 4 + 1];
                float4 t2 = tT4[v * 4 + 2];
                float4 t3 = tT4[v * 4 + 3];
                acc[0]  += t0.x * w1; acc[1]  += t0.y * w1; acc[2]  += t0.z * w1; acc[3]  += t0.w * w1;
                acc[4]  += t1.x * w1; acc[5]  += t1.y * w1; acc[6]  += t1.z * w1; acc[7]  += t1.w * w1;
                acc[8]  += t2.x * w1; acc[9]  += t2.y * w1; acc[10] += t2.z * w1; acc[11] += t2.w * w1;
                acc[12] += t3.x * w1; acc[13] += t3.y * w1; acc[14] += t3.z * w1; acc[15] += t3.w * w1;
            }
            float w2 = tW2[q * VV + w];
#pragma unroll
            for (int bb = 0; bb < BT; bb++) {
                float h = acc[bb];
                h = h > 0.f ? h : expf(h) - 1.f;   // ELU
                fin[bb] = h * w2;
            }
        }
    } else {
        // e-MLP. phase 0: stage ego_t (features 3,4,5, a) for 16 rows
        if (tid < BT) {
            const float* mrow = merged + (size_t)(b0 + tid) * NN * 15;
            esh[tid][0] = mrow[3];
            esh[tid][1] = mrow[4];
            esh[tid][2] = mrow[5];
            esh[tid][3] = a[b0 + tid];
        }
        __syncthreads();
        // phase 1: q1 = relu(ego_t @ eW1 + eb1), stored transposed tT[v*BT+bb]
        if (w < VV) {
            float e0 = eW1[w], e1 = eW1[VV + w], e2 = eW1[2 * VV + w], e3 = eW1[3 * VV + w];
            float bias = eb1[w];
#pragma unroll
            for (int bb = 0; bb < BT; bb++) {
                float qv = bias + esh[bb][0] * e0 + esh[bb][1] * e1 + esh[bb][2] * e2 + esh[bb][3] * e3;
                tT[w * BT + bb] = fmaxf(qv, 0.f);
            }
        }
        __syncthreads();
        // phase 2: relu(q1 @ eW2 + eb2) . eW3
        if (w < VV) {
            float acc[BT];
            float bias = eb2[w];
#pragma unroll
            for (int bb = 0; bb < BT; bb++) acc[bb] = bias;
            const float* W2 = eW2 + w;
            const float4* tT4 = (const float4*)tT;
#pragma unroll 4
            for (int v = 0; v < VV; v++) {
                float w2v = W2[(size_t)v * VV];
                float4 t0 = tT4[v * 4 + 0];
                float4 t1 = tT4[v * 4 + 1];
                float4 t2 = tT4[v * 4 + 2];
                float4 t3 = tT4[v * 4 + 3];
                acc[0]  += t0.x * w2v; acc[1]  += t0.y * w2v; acc[2]  += t0.z * w2v; acc[3]  += t0.w * w2v;
                acc[4]  += t1.x * w2v; acc[5]  += t1.y * w2v; acc[6]  += t1.z * w2v; acc[7]  += t1.w * w2v;
                acc[8]  += t2.x * w2v; acc[9]  += t2.y * w2v; acc[10] += t2.z * w2v; acc[11] += t2.w * w2v;
                acc[12] += t3.x * w2v; acc[13] += t3.y * w2v; acc[14] += t3.z * w2v; acc[15] += t3.w * w2v;
            }
            float w3 = eW3[w];
#pragma unroll
            for (int bb = 0; bb < BT; bb++) fin[bb] = fmaxf(acc[bb], 0.f) * w3;
        }
    }

    // block-reduce fin[16] over threads
#pragma unroll
    for (int bb = 0; bb < BT; bb++)
        for (int off = 32; off; off >>= 1) fin[bb] += __shfl_down(fin[bb], off);
    if (lane == 0)
#pragma unroll
        for (int bb = 0; bb < BT; bb++) redsh[wave * BT + bb] = fin[bb];
    __syncthreads();
    if (tid < BT) {
        float tot = redsh[tid] + redsh[BT + tid] + redsh[2 * BT + tid] + redsh[3 * BT + tid];
        if (q == 3) tot += eb3[0] + tb2[0] + tb2[1] + tb2[2];  // constants added once
        atomicAdd(&out[b0 + tid], tot);
    }
}

extern "C" void kernel_launch(void* const* d_in, const int* in_sizes, int n_in,
                              void* d_out, int out_size, void* d_ws, size_t ws_size,
                              hipStream_t stream) {
    const float* merged = (const float*)d_in[0];
    const float* a      = (const float*)d_in[1];
    const float* upWq   = (const float*)d_in[2];
    const float* upWk   = (const float*)d_in[3];
    const float* upWv   = (const float*)d_in[4];
    const float* dnWq   = (const float*)d_in[5];
    const float* dnWk   = (const float*)d_in[6];
    const float* dnWv   = (const float*)d_in[7];
    const float* pvWq   = (const float*)d_in[8];
    const float* pvWk   = (const float*)d_in[9];
    const float* pvWv   = (const float*)d_in[10];
    const float* tW1    = (const float*)d_in[11];
    const float* tb1    = (const float*)d_in[12];
    const float* tW2    = (const float*)d_in[13];
    const float* tb2    = (const float*)d_in[14];
    const float* eW1    = (const float*)d_in[15];
    const float* eb1    = (const float*)d_in[16];
    const float* eW2    = (const float*)d_in[17];
    const float* eb2    = (const float*)d_in[18];
    const float* eW3    = (const float*)d_in[19];
    const float* eb3    = (const float*)d_in[20];
    const float* gamma  = (const float*)d_in[21];
    const float* beta   = (const float*)d_in[22];
    float* out = (float*)d_out;

    hipMemsetAsync(out, 0, (size_t)out_size * sizeof(float), stream);
    hipLaunchKernelGGL(k_prep, dim3(3), dim3(256), 0, stream, upWq, upWk, dnWq, dnWk, pvWq, pvWk);
    hipLaunchKernelGGL(k_attn, dim3(BB), dim3(256), 0, stream, merged, a, upWv, dnWv, pvWv);
    hipLaunchKernelGGL(k_stats, dim3(75), dim3(256), 0, stream);
    hipLaunchKernelGGL(k_final, dim3(64 * 4), dim3(256), 0, stream, merged, a,
                       tW1, tb1, tW2, tb2, eW1, eb1, eW2, eb2, eW3, eb3, gamma, beta, out);
}